// Round 7
// baseline (101.835 us; speedup 1.0000x reference)
//
#include <hip/hip_runtime.h>
#include <math.h>

#define Bv 256
#define Tv 16
#define Fv 8
#define Dv 32
#define Kv 64
#define Cv 1024
#define Ov 2
#define D1 33   // D+1

typedef unsigned long long u64;
typedef unsigned char u8;

struct SM {
  float xsh[Tv * Fv * Dv];   // [t][ff][j] identity layout, uniform reads only (16 KB)
  u64   cds[Tv];             // packed code bytes per t (u8-aliased writes)
  int   fmask[Tv * Fv];
  int   anyf[Fv][2];         // per-feature per-half match flags
  float srep_all[Fv * D1];
  float vsum[Fv][D1];        // rare-path PV scratch (lower wave only)
};                           // ~19 KB

// ---------------------------------------------------------------------------
// Single kernel: grid = 256 (block = b), 1024 threads = 16 waves (4/SIMD).
// Wave pair (w, w+8) co-owns feature f = w&7: codes t-range and match
// c-range each split in half. 4 block barriers total.
// ---------------------------------------------------------------------------
__global__ __launch_bounds__(1024) void fused(
    const float* __restrict__ tdata, const int* __restrict__ f_mask,
    const float* __restrict__ centers, const int* __restrict__ pat,
    const float* __restrict__ pat_rep, const float* __restrict__ pos_cnt,
    const float* __restrict__ neg_cnt,
    const float* __restrict__ W_q, const float* __restrict__ b_q,
    const float* __restrict__ W_k, const float* __restrict__ b_k,
    const float* __restrict__ W_v, const float* __restrict__ b_v,
    const float* __restrict__ W_pred,
    float* __restrict__ cali, float* __restrict__ a_out,
    float* __restrict__ srep_out) {
  __shared__ SM sm;
  int b = blockIdx.x, tid = threadIdx.x;
  int w = tid >> 6, lane = tid & 63;
  int f = w & 7, half = w >> 3;

  // ---- stage x slab + f_mask (coalesced, identity layout) ----
  {
    const float4* src = (const float4*)(tdata + (size_t)b * (Tv * Fv * Dv));
    ((float4*)sm.xsh)[tid] = src[tid];   // 4096 floats = 1024 float4, one per thread
    if (tid < Tv * Fv) sm.fmask[tid] = f_mask[b * (Tv * Fv) + tid];
  }
  __syncthreads();   // barrier 1

  // ---- codes: wave (f,half) handles t in [half*8, half*8+8), lane = center k ----
  {
    const float4* cp = (const float4*)(centers + (size_t)(f * Kv + lane) * Dv);
    float4 c4[8];
    float cc = 0.f;
    #pragma unroll
    for (int i = 0; i < 8; i++) {
      float4 v = cp[i];
      c4[i] = v;
      cc += v.x * v.x + v.y * v.y + v.z * v.z + v.w * v.w;
    }
    int t0 = half * 8;
    #pragma unroll
    for (int tt = 0; tt < 8; tt += 2) {
      int t = t0 + tt;
      const float4* x0 = (const float4*)&sm.xsh[(t * Fv + f) * Dv];        // uniform
      const float4* x1 = (const float4*)&sm.xsh[((t + 1) * Fv + f) * Dv];  // uniform
      float dot0 = 0.f, dot1 = 0.f;
      #pragma unroll
      for (int i = 0; i < 8; i++) {
        float4 a = x0[i], bq = x1[i];
        dot0 += c4[i].x * a.x + c4[i].y * a.y + c4[i].z * a.z + c4[i].w * a.w;
        dot1 += c4[i].x * bq.x + c4[i].y * bq.y + c4[i].z * bq.z + c4[i].w * bq.w;
      }
      float d0 = cc - 2.0f * dot0;   // ||x||^2 dropped: argmin-invariant
      float d1 = cc - 2.0f * dot1;
      float m0 = d0, m1 = d1;
      #pragma unroll
      for (int off = 1; off <= 32; off <<= 1) {   // two independent chains (ILP)
        m0 = fminf(m0, __shfl_xor(m0, off, 64));
        m1 = fminf(m1, __shfl_xor(m1, off, 64));
      }
      u64 bl0 = __ballot(d0 == m0);
      u64 bl1 = __ballot(d1 == m1);
      int k0 = __ffsll(bl0) - 1;     // lowest lane with min = first-index tiebreak
      int k1 = __ffsll(bl1) - 1;
      if (lane == 0) {
        ((u8*)sm.cds)[t * Fv + f] = sm.fmask[t * Fv + f] ? (u8)(k0 + 2) : (u8)1;
        ((u8*)sm.cds)[(t + 1) * Fv + f] = sm.fmask[(t + 1) * Fv + f] ? (u8)(k1 + 2) : (u8)1;
      }
    }
  }
  __syncthreads();   // barrier 2

  u64 creg[Tv];
  #pragma unroll
  for (int t = 0; t < Tv; t++) creg[t] = sm.cds[t];   // uniform reads

  int fmlv = (lane < Tv) ? sm.fmask[lane * Fv + f] : 0;
  bool fm = __any(fmlv != 0);

  // ---- match: this wave's half = 8 jj, c = (half*8+jj)*64 + lane ----
  unsigned mask8 = 0u;
  #pragma unroll
  for (int jj = 0; jj < 8; jj++) {
    int jj2 = half * 8 + jj;
    int c = (jj2 << 6) + lane;
    const int4* pr = (const int4*)(pat + ((size_t)f * Cv + c) * Fv);
    int4 pa = pr[0], pb = pr[1];
    int vals[8] = {pa.x, pa.y, pa.z, pa.w, pb.x, pb.y, pb.z, pb.w};
    u64 P = 0, M = 0;
    #pragma unroll
    for (int k = 0; k < 8; k++) {
      P |= ((u64)(vals[k] & 0xFF)) << (8 * k);
      if (vals[k] != 0) M |= 0xFFull << (8 * k);
    }
    u64 pm = P & M;
    bool m = false;
    #pragma unroll
    for (int t = 0; t < Tv; t++) m = m || ((creg[t] & M) == pm);
    if (m) mask8 |= (1u << jj);
  }
  bool anyw = __any(mask8 != 0u);
  if (lane == 0) sm.anyf[f][half] = anyw ? 1 : 0;
  __syncthreads();   // barrier 3
  bool anym = (sm.anyf[f][0] | sm.anyf[f][1]) != 0;

  float* arow = a_out + (size_t)(f * Bv + b) * Cv;

  if (!anym) {
    // ---------------- common (degenerate) path: each wave writes its half ----------------
    const float uu = 1.0f / 1024.0f;
    #pragma unroll
    for (int jj = 0; jj < 8; jj++) arow[((half * 8 + jj) << 6) + lane] = uu;
    if (half == 0 && lane < D1) {
      float vd = fm ? b_v[f * D1 + lane] : 0.f;
      srep_out[(b * Fv + f) * D1 + lane] = vd;
      sm.srep_all[f * D1 + lane] = vd;
    }
  } else if (half == 0) {
    // ---------------- rare full path: lower wave alone, full 1024 c, no barriers ----------------
    unsigned mask16 = 0u;
    #pragma unroll 4
    for (int jj = 0; jj < 16; jj++) {
      int c = (jj << 6) + lane;
      const int4* pr = (const int4*)(pat + ((size_t)f * Cv + c) * Fv);
      int4 pa = pr[0], pb = pr[1];
      int vals[8] = {pa.x, pa.y, pa.z, pa.w, pb.x, pb.y, pb.z, pb.w};
      u64 P = 0, M = 0;
      #pragma unroll
      for (int k = 0; k < 8; k++) {
        P |= ((u64)(vals[k] & 0xFF)) << (8 * k);
        if (vals[k] != 0) M |= 0xFFull << (8 * k);
      }
      u64 pm = P & M;
      bool m = false;
      #pragma unroll
      for (int t = 0; t < Tv; t++) m = m || ((creg[t] & M) == pm);
      if (m) mask16 |= (1u << jj);
    }
    if (lane < D1) sm.vsum[f][lane] = 0.f;
    float iqv = 0.f;
    if (lane < Dv) {
      const float* wq = W_q + (f * Dv + lane) * Dv;
      const float* xq = &sm.xsh[((Tv - 1) * Fv + f) * Dv];
      float s = b_q[f * Dv + lane];
      for (int j = 0; j < Dv; j++) s += wq[j] * xq[j];
      iqv = s;
    }
    float zv = 0.f;   // z_j (lane<33) and bk·iq (lane 33) via shfl broadcast of iq
    for (int i = 0; i < Dv; i++) {
      float iqi = __shfl(iqv, i, 64);
      float coef = 0.f;
      if (lane < D1) coef = W_k[(f * Dv + i) * D1 + lane];
      else if (lane == D1) coef = b_k[f * Dv + i];
      zv += coef * iqi;
    }
    float ev[16];
    float lmax = -INFINITY;
    for (int jj = 0; jj < 16; jj++) {
      ev[jj] = 0.f;
      if (mask16 & (1u << jj)) {
        int c = (jj << 6) + lane;
        const float* rp = pat_rep + ((size_t)f * Cv + c) * Dv;
        float p = pos_cnt[f * Cv + c], n = neg_cnt[f * Cv + c];
        float r = p / (p + n + 1e-6f);
        float s = __shfl(zv, D1, 64) + r * __shfl(zv, Dv, 64);
        for (int j = 0; j < Dv; j++) s += rp[j] * __shfl(zv, j, 64);
        ev[jj] = s;
        lmax = fmaxf(lmax, s);
      }
    }
    float bm = lmax;
    #pragma unroll
    for (int off = 1; off <= 32; off <<= 1) bm = fmaxf(bm, __shfl_xor(bm, off, 64));
    float ls = 0.f;
    for (int jj = 0; jj < 16; jj++) {
      if (mask16 & (1u << jj)) { ev[jj] = expf(ev[jj] - bm); ls += ev[jj]; }
    }
    float Zs = ls;
    #pragma unroll
    for (int off = 1; off <= 32; off <<= 1) Zs += __shfl_xor(Zs, off, 64);
    for (int jj = 0; jj < 16; jj++) {
      int c = (jj << 6) + lane;
      bool hit = (mask16 & (1u << jj)) != 0u;
      float a = hit ? ev[jj] / Zs : 0.f;   // unmatched: exact 0 (ref: exp underflow)
      arow[c] = a;
      if (hit && a != 0.f) {
        const float* rp = pat_rep + ((size_t)f * Cv + c) * Dv;
        float p = pos_cnt[f * Cv + c], n = neg_cnt[f * Cv + c];
        float r = p / (p + n + 1e-6f);
        for (int j = 0; j < Dv; j++) atomicAdd(&sm.vsum[f][j], a * rp[j]);
        atomicAdd(&sm.vsum[f][Dv], a * r);
      }
    }
    if (lane < D1) {   // v = Wv·(sum a·rep) + bv
      float s = b_v[f * D1 + lane];
      const float* wvp = W_v + (f * D1 + lane) * D1;
      for (int j = 0; j < D1; j++) s += wvp[j] * sm.vsum[f][j];
      float vd = fm ? s : 0.f;
      srep_out[(b * Fv + f) * D1 + lane] = vd;
      sm.srep_all[f * D1 + lane] = vd;
    }
  }

  __syncthreads();   // barrier 4
  // ---- cali: wave 0, 32 lanes per output o ----
  if (tid < 64) {
    int o = tid >> 5, l = tid & 31;
    const float* wp = W_pred + o * (Fv * D1);
    float acc = 0.f;
    for (int i = l; i < Fv * D1; i += 32) acc += sm.srep_all[i] * wp[i];
    #pragma unroll
    for (int off = 16; off >= 1; off >>= 1) acc += __shfl_xor(acc, off, 64);
    if (l == 0) cali[b * Ov + o] = acc;
  }
}

extern "C" void kernel_launch(void* const* d_in, const int* in_sizes, int n_in,
                              void* d_out, int out_size, void* d_ws, size_t ws_size,
                              hipStream_t stream) {
  const float* tdata   = (const float*)d_in[0];
  const int*   f_mask  = (const int*)d_in[1];
  const float* centers = (const float*)d_in[2];
  const int*   pat     = (const int*)d_in[3];
  const float* pat_rep = (const float*)d_in[4];
  const float* pos_cnt = (const float*)d_in[5];
  const float* neg_cnt = (const float*)d_in[6];
  const float* W_q     = (const float*)d_in[7];
  const float* b_q     = (const float*)d_in[8];
  const float* W_k     = (const float*)d_in[9];
  const float* b_k     = (const float*)d_in[10];
  const float* W_v     = (const float*)d_in[11];
  const float* b_v     = (const float*)d_in[12];
  const float* W_pred  = (const float*)d_in[13];

  float* out = (float*)d_out;
  float* cali = out;                                        // Bv*Ov
  float* a_all = out + (Bv * Ov);                           // Fv*Bv*Cv
  float* srep = out + (Bv * Ov) + (Fv * (size_t)Bv * Cv);   // Bv*Fv*D1

  fused<<<Bv, 1024, 0, stream>>>(
      tdata, f_mask, centers, pat, pat_rep, pos_cnt, neg_cnt,
      W_q, b_q, W_k, b_k, W_v, b_v, W_pred,
      cali, a_all, srep);
}